// Round 5
// baseline (499.113 us; speedup 1.0000x reference)
//
#include <hip/hip_runtime.h>
#include <math.h>

#define EPS 1e-6f

// Native clang vector type — __builtin_nontemporal_load requires a pointer to
// a scalar or clang ext_vector, not HIP's struct-wrapper int4.
typedef int  v4i __attribute__((ext_vector_type(4)));

// 12-byte vertex record, dword-aligned -> one global_load_dwordx3 per vertex
// (4 gather instructions per edge instead of 12 scalar dword loads).
struct __attribute__((packed, aligned(4))) Vert3 { float x, y, z; };

__device__ __forceinline__ float edge_cos(const Vert3* __restrict__ v,
                                          int i0, int i1, int i2, int i3) {
    Vert3 p0 = v[i0];
    Vert3 p1 = v[i1];
    Vert3 p2 = v[i2];
    Vert3 p3 = v[i3];

    float ax = p1.x - p0.x, ay = p1.y - p0.y, az = p1.z - p0.z;
    float bx = p2.x - p0.x, by = p2.y - p0.y, bz = p2.z - p0.z;
    float cx = p3.x - p0.x, cy = p3.y - p0.y, cz = p3.z - p0.z;

    float al2 = ax*ax + ay*ay + az*az;
    float al1 = sqrtf(al2 + EPS);

    // wing(a, b)
    float bl2 = bx*bx + by*by + bz*bz;
    float bl1 = sqrtf(bl2 + EPS);
    float ab  = ax*bx + ay*by + az*bz;
    float cos1 = ab / (al1 * bl1 + EPS);
    float sin1 = sqrtf(1.0f - cos1*cos1 + EPS);
    float t1   = ab / (al2 + EPS);
    float cb1x = bx - ax*t1, cb1y = by - ay*t1, cb1z = bz - az*t1;
    float cb1l = bl1 * sin1;

    // wing(a, c)
    float cl2 = cx*cx + cy*cy + cz*cz;
    float cl1 = sqrtf(cl2 + EPS);
    float ac  = ax*cx + ay*cy + az*cz;
    float cos2 = ac / (al1 * cl1 + EPS);
    float sin2 = sqrtf(1.0f - cos2*cos2 + EPS);
    float t2   = ac / (al2 + EPS);
    float cb2x = cx - ax*t2, cb2y = cy - ay*t2, cb2z = cz - az*t2;
    float cb2l = cl1 * sin2;

    float num = cb1x*cb2x + cb1y*cb2y + cb1z*cb2z;
    return num / (cb1l * cb2l + EPS);
}

// One quad (4 edges, 16 vertex gathers) per thread, no loop: all gathers
// issue before any use -> max MLP; grid sized to cover nquad exactly.
// Index loads + cos stores nontemporal (zero reuse) so the 24 MB vertex
// table stays L2/L3-resident for the 24M random gathers.
__global__ __launch_bounds__(256) void soft_flatten_main(
    const Vert3* __restrict__ verts,
    const int* __restrict__ v0s, const int* __restrict__ v1s,
    const int* __restrict__ v2s, const int* __restrict__ v3s,
    float* __restrict__ cos_out,    // d_out + 1, E floats (4B-aligned only)
    double* __restrict__ partials,  // d_ws, one double per block
    int nquad)
{
    const int q = blockIdx.x * blockDim.x + threadIdx.x;

    double acc = 0.0;

    if (q < nquad) {
        v4i i0 = __builtin_nontemporal_load((const v4i*)v0s + q);
        v4i i1 = __builtin_nontemporal_load((const v4i*)v1s + q);
        v4i i2 = __builtin_nontemporal_load((const v4i*)v2s + q);
        v4i i3 = __builtin_nontemporal_load((const v4i*)v3s + q);

        float c0 = edge_cos(verts, i0.x, i1.x, i2.x, i3.x);
        float c1 = edge_cos(verts, i0.y, i1.y, i2.y, i3.y);
        float c2 = edge_cos(verts, i0.z, i1.z, i2.z, i3.z);
        float c3 = edge_cos(verts, i0.w, i1.w, i2.w, i3.w);

        int base = q << 2;
        // d_out+1 is only 4B-aligned -> scalar stores; wave still covers a
        // contiguous 1024-float span.
        __builtin_nontemporal_store(c0, cos_out + base + 0);
        __builtin_nontemporal_store(c1, cos_out + base + 1);
        __builtin_nontemporal_store(c2, cos_out + base + 2);
        __builtin_nontemporal_store(c3, cos_out + base + 3);

        float d0 = c0 + 1.0f, d1 = c1 + 1.0f, d2 = c2 + 1.0f, d3 = c3 + 1.0f;
        acc = (double)(d0*d0) + (double)(d1*d1)
            + (double)(d2*d2) + (double)(d3*d3);
    }

    // wave (64-lane) shuffle reduction in double
    #pragma unroll
    for (int off = 32; off > 0; off >>= 1)
        acc += __shfl_down(acc, off, 64);

    __shared__ double smem[4];
    int wid  = threadIdx.x >> 6;
    int lane = threadIdx.x & 63;
    if (lane == 0) smem[wid] = acc;
    __syncthreads();
    if (threadIdx.x == 0)
        partials[blockIdx.x] = smem[0] + smem[1] + smem[2] + smem[3];
}

// Final reduction: 1 block sums per-block partials (double) into d_out[0].
__global__ __launch_bounds__(256) void soft_flatten_reduce(
    const double* __restrict__ partials, int n, float* __restrict__ out)
{
    double acc = 0.0;
    for (int i = threadIdx.x; i < n; i += 256)
        acc += partials[i];

    #pragma unroll
    for (int off = 32; off > 0; off >>= 1)
        acc += __shfl_down(acc, off, 64);

    __shared__ double smem[4];
    int wid  = threadIdx.x >> 6;
    int lane = threadIdx.x & 63;
    if (lane == 0) smem[wid] = acc;
    __syncthreads();
    if (threadIdx.x == 0)
        out[0] = (float)(smem[0] + smem[1] + smem[2] + smem[3]);
}

extern "C" void kernel_launch(void* const* d_in, const int* in_sizes, int n_in,
                              void* d_out, int out_size, void* d_ws, size_t ws_size,
                              hipStream_t stream) {
    const Vert3* verts = (const Vert3*)d_in[0];
    const int*   v0s   = (const int*)d_in[1];
    const int*   v1s   = (const int*)d_in[2];
    const int*   v2s   = (const int*)d_in[3];
    const int*   v3s   = (const int*)d_in[4];

    const int nE    = in_sizes[1];        // 6,000,000 edges (divisible by 4)
    const int nquad = nE >> 2;            // 1,500,000
    float* loss_out = (float*)d_out;      // [0] = loss
    float* cos_out  = (float*)d_out + 1;  // [1..E] = cos_ori

    const int BLOCKS = (nquad + 255) / 256;   // 5860: one quad per thread
    soft_flatten_main<<<BLOCKS, 256, 0, stream>>>(
        verts, v0s, v1s, v2s, v3s, cos_out, (double*)d_ws, nquad);
    soft_flatten_reduce<<<1, 256, 0, stream>>>(
        (const double*)d_ws, BLOCKS, loss_out);
}